// Round 10
// baseline (247.528 us; speedup 1.0000x reference)
//
#include <hip/hip_runtime.h>
#include <hip/hip_bf16.h>

typedef __hip_bfloat16 bf16;
typedef __attribute__((ext_vector_type(8))) short bfrag8;   // 8 bf16 = 4 VGPRs
typedef __attribute__((ext_vector_type(4))) float f4;
typedef __attribute__((ext_vector_type(16))) float f16v;    // 32x32 accumulator

#define NN 32704      // total nodes = 64 trees * 511
#define MP 32768      // M padded to 128-multiple
#define PT 511
#define NT 64
#define XD 640

union bfu8 { bfrag8 v; bf16 h[8]; };
union bfu4 { uint2 u; bf16 h[4]; };

__device__ __forceinline__ float fast_sigmoid(float x) {
    float e = exp2f(-1.44269504f * x);
    return __builtin_amdgcn_rcpf(1.0f + e);
}
__device__ __forceinline__ float fast_tanh(float x) {
    float e = exp2f(2.88539008f * x);
    return 1.0f - 2.0f * __builtin_amdgcn_rcpf(e + 1.0f);
}

// async global->LDS, 16B/lane. LDS dest linear; swizzle applied on GLOBAL source (m173).
__device__ __forceinline__ void gload16(const bf16* g, char* l) {
    __builtin_amdgcn_global_load_lds(
        (const __attribute__((address_space(1))) unsigned int*)(g),
        (__attribute__((address_space(3))) unsigned int*)(l), 16, 0, 0);
}

// ---------------- weight transpose-convert: all 12 weights, one launch ----------------
struct WtSeg { const float* src; bf16* dst; int K, Nc, kpad, tile0; };
struct WtArgs { WtSeg s[12]; };
__global__ __launch_bounds__(256) void wt_kernel(WtArgs a) {
    int bid = blockIdx.x;
    int si = 0;
#pragma unroll
    for (int i = 1; i < 12; ++i) if (bid >= a.s[i].tile0) si = i;
    WtSeg sg = a.s[si];
    int local = bid - sg.tile0;
    int kt = sg.kpad >> 6;
    int nb = local / kt, kb = local - nb * kt;
    int n0 = nb * 64, k0 = kb * 64;

    __shared__ float T[64][65];
    int tid = threadIdx.x;
    int kk = tid >> 2, nq = (tid & 3) * 16;
    bool kval = (k0 + kk) < sg.K;
    const float* srow = sg.src + (size_t)(k0 + kk) * sg.Nc + n0 + nq;
#pragma unroll
    for (int c = 0; c < 4; ++c) {
        float4 v = kval ? *(const float4*)(srow + c * 4) : float4{0, 0, 0, 0};
        T[kk][nq + c * 4 + 0] = v.x; T[kk][nq + c * 4 + 1] = v.y;
        T[kk][nq + c * 4 + 2] = v.z; T[kk][nq + c * 4 + 3] = v.w;
    }
    __syncthreads();
    int n = tid >> 2;
#pragma unroll
    for (int c = 0; c < 2; ++c) {
        int k8 = (tid & 3) * 2 + c;
        bfu8 u;
#pragma unroll
        for (int j = 0; j < 8; ++j) u.h[j] = __float2bfloat16(T[k8 * 8 + j][n]);
        *(bfrag8*)(sg.dst + (size_t)(n0 + n) * sg.kpad + k0 + k8 * 8) = u.v;
    }
}

// ---------------- fused MLP: f32-feat inline convert + 2 layers, hid1 in LDS ----------------
struct MlpP { const float* feat; const bf16* w1; const float* b1; const bf16* w2; const float* b2; };
struct MlpArgs { MlpP p[5]; int din[5]; int kpad[5]; };
__global__ __launch_bounds__(256) void mlp_kernel(MlpArgs args, bf16* __restrict__ out) {
    __shared__ __align__(16) char smem[64 * 1024];
    char* As = smem;            // [128][128B] feat k-tile (bf16, swizzled)
    char* Bs = smem + 16384;    // [128][128B] w1 k-tile
    char* Hs = smem + 32768;    // [128][256B] hid1 (bf16, swizzled)
    int t = blockIdx.y;
    int K = args.kpad[t], din = args.din[t];
    MlpP p = args.p[t];
    int tid = threadIdx.x, lane = tid & 63, w = tid >> 6;
    int brow = blockIdx.x * 128;
    int wr = (w >> 1) * 64, wc = (w & 1) * 64;
    int am = lane & 15, ah = lane >> 4;

    f4 acc[4][4] = {};
    for (int k0 = 0; k0 < K; k0 += 64) {
#pragma unroll
        for (int r = 0; r < 4; ++r) {
            int o = r * 4096 + tid * 16;
            int row = o >> 7;
            int cb = (o & 127) ^ ((row & 7) << 4);
            gload16(p.w1 + (size_t)row * K + k0 + (cb >> 1), Bs + o);
        }
        {
            int col0 = (tid & 7) * 8;
#pragma unroll
            for (int c = 0; c < 4; ++c) {
                int row = (tid >> 3) + c * 32;
                int grow = brow + row;
                bfu8 u; u.v = (bfrag8){0,0,0,0,0,0,0,0};
                int kc = k0 + col0;
                if (grow < NN && kc < din) {
                    const float* s = p.feat + (size_t)grow * din + kc;
                    float4 x = *(const float4*)s, y = *(const float4*)(s + 4);
                    u.h[0] = __float2bfloat16(x.x); u.h[1] = __float2bfloat16(x.y);
                    u.h[2] = __float2bfloat16(x.z); u.h[3] = __float2bfloat16(x.w);
                    u.h[4] = __float2bfloat16(y.x); u.h[5] = __float2bfloat16(y.y);
                    u.h[6] = __float2bfloat16(y.z); u.h[7] = __float2bfloat16(y.w);
                }
                *(bfrag8*)(As + row * 128 + ((col0 * 2) ^ ((row & 7) << 4))) = u.v;
            }
        }
        __syncthreads();
#pragma unroll
        for (int s = 0; s < 2; ++s) {
            int cb = s * 64 + ah * 16;
            bfrag8 a[4], b[4];
#pragma unroll
            for (int f = 0; f < 4; ++f) {
                int ra = wr + f * 16 + am;
                a[f] = *(const bfrag8*)(As + ra * 128 + (cb ^ ((ra & 7) << 4)));
                int rb = wc + f * 16 + am;
                b[f] = *(const bfrag8*)(Bs + rb * 128 + (cb ^ ((rb & 7) << 4)));
            }
#pragma unroll
            for (int i = 0; i < 4; ++i)
#pragma unroll
                for (int j = 0; j < 4; ++j)
                    acc[i][j] = __builtin_amdgcn_mfma_f32_16x16x32_bf16(a[i], b[j], acc[i][j], 0, 0, 0);
        }
        __syncthreads();
    }
#pragma unroll
    for (int i = 0; i < 4; ++i)
#pragma unroll
        for (int j = 0; j < 4; ++j) {
            int col = wc + j * 16 + am;
            float bb = p.b1[col];
#pragma unroll
            for (int r = 0; r < 4; ++r) {
                int row = wr + i * 16 + ah * 4 + r;
                float v = fmaxf(acc[i][j][r] + bb, 0.0f);
                *(bf16*)(Hs + row * 256 + ((col * 2) ^ ((row & 7) << 4))) = __float2bfloat16(v);
            }
        }
    __syncthreads();
    f4 acc2[4][4] = {};
#pragma unroll
    for (int ks = 0; ks < 4; ++ks) {
        bfrag8 a[4], b[4];
        int kb = ks * 64 + ah * 16;
#pragma unroll
        for (int f = 0; f < 4; ++f) {
            int ra = wr + f * 16 + am;
            a[f] = *(const bfrag8*)(Hs + ra * 256 + (kb ^ ((ra & 7) << 4)));
            int cbn = wc + f * 16 + am;
            b[f] = *(const bfrag8*)(p.w2 + (size_t)cbn * 128 + ks * 32 + ah * 8);
        }
#pragma unroll
        for (int i = 0; i < 4; ++i)
#pragma unroll
            for (int j = 0; j < 4; ++j)
                acc2[i][j] = __builtin_amdgcn_mfma_f32_16x16x32_bf16(a[i], b[j], acc2[i][j], 0, 0, 0);
    }
#pragma unroll
    for (int i = 0; i < 4; ++i)
#pragma unroll
        for (int j = 0; j < 4; ++j) {
            int col = wc + j * 16 + am;
            float bb = p.b2[col];
#pragma unroll
            for (int r = 0; r < 4; ++r) {
                int row = brow + wr + i * 16 + ah * 4 + r;
                float v = fmaxf(acc2[i][j][r] + bb, 0.0f);
                out[(size_t)row * XD + t * 128 + col] = __float2bfloat16(v);
            }
        }
}

// ---------------- xou GEMM: r7 schedule (2-buf BK=64 counted-vmcnt), 32x32x16 MFMA ----------
// 1D grid 2560, bijective XCD swizzle; per wave 64 rows x 32 cols x 3q = 2x1 tiles of 32x32,
// 24 MFMA/K-tile (vs 48 of 16x16x32) at the higher 32x32 rate (m119: 2495 vs 2176 TF).
// C/D layout (m74/m101, HW-verified): col = lane&31, row = (r&3) + 8*(r>>2) + 4*(lane>>5).
__global__ __launch_bounds__(256) void xou_kernel(
    const bf16* __restrict__ X, const bf16* __restrict__ Wt,
    const float* __restrict__ bias,
    bf16* __restrict__ ffp, bf16* __restrict__ rrp, float* __restrict__ cc)
{
    __shared__ __align__(16) char smem[80 * 1024];   // 2 x (A 16K + B 24K)
    int bid = blockIdx.x;
    int swz = (bid & 7) * 320 + (bid >> 3);          // bijective XCD swizzle, nwg=2560
    int bcol = (swz % 10) * 64;
    int brow = (swz / 10) * 128;
    int tid = threadIdx.x, lane = tid & 63, w = tid >> 6;
    int wr = (w >> 1) * 64, wc = (w & 1) * 32;
    int lm = lane & 31, hi = lane >> 5;

    auto stage = [&](int buf, int k0) {   // 10 load instructions per lane (unchanged)
        char* As = smem + buf * 40960;
        char* Bs = As + 16384;
#pragma unroll
        for (int r = 0; r < 4; ++r) {
            int o = r * 4096 + tid * 16;
            int row = o >> 7;
            int cb = (o & 127) ^ ((row & 7) << 4);
            gload16(X + (size_t)(brow + row) * XD + k0 + (cb >> 1), As + o);
        }
#pragma unroll
        for (int r = 0; r < 6; ++r) {
            int o = r * 4096 + tid * 16;
            int row = o >> 7;
            int q = row >> 6, rl = row & 63;
            int cb = (o & 127) ^ ((row & 7) << 4);
            gload16(Wt + (size_t)(q * 640 + bcol + rl) * XD + k0 + (cb >> 1), Bs + o);
        }
    };

    f16v acc[3][2] = {};
    auto compute = [&](int buf) {
        char* As = smem + buf * 40960;
        char* Bs = As + 16384;
#pragma unroll
        for (int s = 0; s < 4; ++s) {                // K-steps of 16
            int cb = s * 32 + hi * 16;               // 16B frag at k = s*16 + hi*8
            bfrag8 a[2], b[3];
#pragma unroll
            for (int i = 0; i < 2; ++i) {
                int ra = wr + i * 32 + lm;
                a[i] = *(const bfrag8*)(As + ra * 128 + (cb ^ ((ra & 7) << 4)));
            }
#pragma unroll
            for (int q = 0; q < 3; ++q) {
                int rb = q * 64 + wc + lm;
                b[q] = *(const bfrag8*)(Bs + rb * 128 + (cb ^ ((rb & 7) << 4)));
            }
            __builtin_amdgcn_s_setprio(1);
#pragma unroll
            for (int q = 0; q < 3; ++q)
#pragma unroll
                for (int i = 0; i < 2; ++i)
                    acc[q][i] = __builtin_amdgcn_mfma_f32_32x32x16_bf16(a[i], b[q], acc[q][i], 0, 0, 0);
            __builtin_amdgcn_s_setprio(0);
        }
    };

    stage(0, 0);
    stage(1, 64);
    for (int kt = 0; kt < 8; ++kt) {
        asm volatile("s_waitcnt vmcnt(10)" ::: "memory");  // tile kt landed; kt+1 in flight
        __builtin_amdgcn_s_barrier();
        compute(kt & 1);
        __builtin_amdgcn_s_barrier();                      // all waves done reading before overwrite
        stage(kt & 1, (kt + 2) * 64);
    }
    asm volatile("s_waitcnt vmcnt(10)" ::: "memory");
    __builtin_amdgcn_s_barrier();
    compute(0);
    asm volatile("s_waitcnt vmcnt(0)" ::: "memory");
    __builtin_amdgcn_s_barrier();
    compute(1);

    // epilogue: col fixed per lane; 16 regs span rows {(r&3)+8*(r>>2)+4*hi}
    int col = bcol + wc + lm;
    float bxx = bias[col], bff = bias[640 + col], brr = bias[1280 + col];
#pragma unroll
    for (int i = 0; i < 2; ++i)
#pragma unroll
        for (int r = 0; r < 16; ++r) {
            int row = brow + wr + i * 32 + (r & 3) + 8 * (r >> 2) + 4 * hi;
            size_t o = (size_t)row * XD + col;
            float xx = acc[0][i][r] + bxx;
            float fv = fast_sigmoid(acc[1][i][r] + bff);
            float rv = fast_sigmoid(acc[2][i][r] + brr);
            unsigned pl = (unsigned)row % 511u;
            if (pl < 255u) ffp[o] = __float2bfloat16(fv);  // ff read only for internal nodes
            rrp[o] = __float2bfloat16(rv);
            if (row < NN) cc[o] = (1.0f - fv) * xx;
        }
}

// ---------------- tree recursion in LDS + h, one launch ----------------
__device__ __forceinline__ int clidx(int node, int e) {
    int g = e & ~3;
    return node * 32 + (g ^ ((node & 7) * 4)) + (e & 3);
}
__global__ __launch_bounds__(256) void levels_h_kernel(
    float* __restrict__ c, const bf16* __restrict__ ff,
    const bf16* __restrict__ rr, const bf16* __restrict__ x, bf16* __restrict__ h) {
    __shared__ __align__(16) float cl[511 * 32];   // 65,408 B
    int t = blockIdx.x, d0 = blockIdx.y * 32;
    size_t tb = (size_t)t * PT;
    int tid = threadIdx.x;

    for (int it = tid; it < 511 * 8; it += 256) {
        int node = it >> 3, q = (it & 7) * 4;
        *(float4*)&cl[clidx(node, q)] = *(const float4*)(c + (tb + node) * XD + d0 + q);
    }
    __syncthreads();

    for (int n = 1; n <= 8; ++n) {
        int cnt = 1 << (8 - n);
        for (int it = tid; it < cnt * 8; it += 256) {
            int pl = (cnt - 1) + (it >> 3), q = (it & 7) * 4;
            bfu4 fu; fu.u = *(const uint2*)(ff + (tb + pl) * XD + d0 + q);
            float4 l  = *(const float4*)&cl[clidx(2 * pl + 1, q)];
            float4 rg = *(const float4*)&cl[clidx(2 * pl + 2, q)];
            float4 cv = *(const float4*)&cl[clidx(pl, q)];
            cv.x += __bfloat162float(fu.h[0]) * (l.x + rg.x);
            cv.y += __bfloat162float(fu.h[1]) * (l.y + rg.y);
            cv.z += __bfloat162float(fu.h[2]) * (l.z + rg.z);
            cv.w += __bfloat162float(fu.h[3]) * (l.w + rg.w);
            *(float4*)&cl[clidx(pl, q)] = cv;
        }
        __syncthreads();
    }

    for (int it = tid; it < 255 * 8; it += 256) {
        int pl = it >> 3, q = (it & 7) * 4;
        *(float4*)(c + (tb + pl) * XD + d0 + q) = *(const float4*)&cl[clidx(pl, q)];
    }
    for (int it = tid; it < 511 * 4; it += 256) {
        int node = it >> 2, q = (it & 3) * 8;
        size_t o = (tb + node) * XD + d0 + q;
        bfu8 rv, xv, ov;
        rv.v = *(const bfrag8*)(rr + o);
        xv.v = *(const bfrag8*)(x + o);
        float4 c0 = *(const float4*)&cl[clidx(node, q)];
        float4 c1 = *(const float4*)&cl[clidx(node, q + 4)];
        float cv[8] = {c0.x, c0.y, c0.z, c0.w, c1.x, c1.y, c1.z, c1.w};
#pragma unroll
        for (int j = 0; j < 8; ++j) {
            float r = __bfloat162float(rv.h[j]);
            float xb = __bfloat162float(xv.h[j]);
            ov.h[j] = __float2bfloat16(r * fast_tanh(cv[j]) + (1.0f - r) * xb);
        }
        *(bfrag8*)(h + o) = ov.v;
    }
}

// ---------------- o1 GEMM fused with w_o2 dot: atomicAdd partial row sums ----------------
__global__ __launch_bounds__(256) void gemm_db_kernel(
    const bf16* __restrict__ A, const bf16* __restrict__ Bt,
    const float* __restrict__ bias, const float* __restrict__ w2,
    float* __restrict__ outacc)
{
    __shared__ __align__(16) char smem[64 * 1024];
    int bid = blockIdx.x;
    int swz = (bid & 7) * 128 + (bid >> 3);          // bijective, nwg=1024
    int bcol = (swz & 3) * 128;
    int brow = (swz >> 2) * 128;
    int tid = threadIdx.x, lane = tid & 63, w = tid >> 6;
    int wr = (w >> 1) * 64, wc = (w & 1) * 64;
    int am = lane & 15, ah = lane >> 4;

    auto stage = [&](int buf, int k0) {
        char* As = smem + buf * 32768;
        char* Bs = As + 16384;
#pragma unroll
        for (int r = 0; r < 4; ++r) {
            int o = r * 4096 + tid * 16;
            int row = o >> 7;
            int cb = (o & 127) ^ ((row & 7) << 4);
            gload16(A + (size_t)(brow + row) * XD + k0 + (cb >> 1), As + o);
            gload16(Bt + (size_t)(bcol + row) * XD + k0 + (cb >> 1), Bs + o);
        }
    };

    f4 acc[4][4] = {};
    auto compute = [&](int buf) {
        char* As = smem + buf * 32768;
        char* Bs = As + 16384;
#pragma unroll
        for (int s = 0; s < 2; ++s) {
            int cb = s * 64 + ah * 16;
            bfrag8 a[4], b[4];
#pragma unroll
            for (int f = 0; f < 4; ++f) {
                int ra = wr + f * 16 + am;
                a[f] = *(const bfrag8*)(As + ra * 128 + (cb ^ ((ra & 7) << 4)));
                int rb = wc + f * 16 + am;
                b[f] = *(const bfrag8*)(Bs + rb * 128 + (cb ^ ((rb & 7) << 4)));
            }
            __builtin_amdgcn_s_setprio(1);
#pragma unroll
            for (int i = 0; i < 4; ++i)
#pragma unroll
                for (int j = 0; j < 4; ++j)
                    acc[i][j] = __builtin_amdgcn_mfma_f32_16x16x32_bf16(a[i], b[j], acc[i][j], 0, 0, 0);
            __builtin_amdgcn_s_setprio(0);
        }
    };

    stage(0, 0);
    stage(1, 64);
    for (int kt = 0; kt < 8; ++kt) {
        asm volatile("s_waitcnt vmcnt(8)" ::: "memory");
        __builtin_amdgcn_s_barrier();
        compute(kt & 1);
        __builtin_amdgcn_s_barrier();
        stage(kt & 1, (kt + 2) * 64);
    }
    asm volatile("s_waitcnt vmcnt(8)" ::: "memory");
    __builtin_amdgcn_s_barrier();
    compute(0);
    asm volatile("s_waitcnt vmcnt(0)" ::: "memory");
    __builtin_amdgcn_s_barrier();
    compute(1);

    // epilogue: hid2 = relu(acc+bias); partial dot with w_o2 cols; reduce over 16 lanes; atomic
    float w2v[4];
#pragma unroll
    for (int j = 0; j < 4; ++j) w2v[j] = w2[bcol + wc + j * 16 + am];
#pragma unroll
    for (int i = 0; i < 4; ++i) {
        float ps[4] = {0.0f, 0.0f, 0.0f, 0.0f};
#pragma unroll
        for (int j = 0; j < 4; ++j) {
            float bb = bias[bcol + wc + j * 16 + am];
#pragma unroll
            for (int r = 0; r < 4; ++r)
                ps[r] += fmaxf(acc[i][j][r] + bb, 0.0f) * w2v[j];
        }
#pragma unroll
        for (int r = 0; r < 4; ++r) {
            float s = ps[r];
            s += __shfl_xor(s, 1, 64);
            s += __shfl_xor(s, 2, 64);
            s += __shfl_xor(s, 4, 64);
            s += __shfl_xor(s, 8, 64);
            if (am == 0) {
                int row = brow + wr + i * 16 + ah * 4 + r;
                if (row < NN) atomicAdd(outacc + row, s);
            }
        }
    }
}

// ---------------- out = sigmoid(acc + b_o2) ----------------
__global__ void sig_kernel(const float* __restrict__ acc, const float* __restrict__ b2,
                           float* __restrict__ out) {
    int i = blockIdx.x * 256 + threadIdx.x;
    if (i < NN) out[i] = fast_sigmoid(acc[i] + b2[0]);
}

// ---------------- host ----------------
extern "C" void kernel_launch(void* const* d_in, const int* in_sizes, int n_in,
                              void* d_out, int out_size, void* d_ws, size_t ws_size,
                              hipStream_t stream) {
    const int din[5]  = {32, 64, 256, 128, 16};
    const int kpad[5] = {64, 64, 256, 128, 64};

    const float* feats[5];
    const float *w1f[5], *b1f[5], *w2f[5], *b2f[5];
    for (int t = 0; t < 5; ++t) {
        feats[t] = (const float*)d_in[t];
        w1f[t] = (const float*)d_in[8 + 4 * t];
        b1f[t] = (const float*)d_in[9 + 4 * t];
        w2f[t] = (const float*)d_in[10 + 4 * t];
        b2f[t] = (const float*)d_in[11 + 4 * t];
    }
    const float* w_xou = (const float*)d_in[28];
    const float* b_xou = (const float*)d_in[29];
    const float* w_o1  = (const float*)d_in[30];
    const float* b_o1  = (const float*)d_in[31];
    const float* w_o2  = (const float*)d_in[32];
    const float* b_o2  = (const float*)d_in[33];

    float* outp = (float*)d_out;
    float* cc   = (float*)d_out + NN;

    char* ws = (char*)d_ws;
    size_t off = 0;
    auto take = [&](size_t bytes) -> char* {
        char* p = ws + off;
        off += (bytes + 255) & ~(size_t)255;
        return p;
    };
    bf16* w1t[5]; for (int t = 0; t < 5; ++t) w1t[t] = (bf16*)take((size_t)128 * kpad[t] * 2);
    bf16* w2t[5]; for (int t = 0; t < 5; ++t) w2t[t] = (bf16*)take((size_t)128 * 128 * 2);
    bf16* wxout = (bf16*)take((size_t)1920 * 640 * 2);
    bf16* wo1t  = (bf16*)take((size_t)512 * 640 * 2);
    bf16* hbf   = (bf16*)take((size_t)MP * XD * 2);
    bf16* xbf   = (bf16*)take((size_t)MP * XD * 2);
    bf16* ffb   = (bf16*)take((size_t)MP * XD * 2);
    bf16* rrb   = (bf16*)take((size_t)MP * XD * 2);
    float* outacc = (float*)take((size_t)MP * 4);

    // 1) weight transpose-converts (one launch)
    WtArgs wa;
    int t0 = 0, si = 0;
    auto addseg = [&](const float* s, bf16* d, int K, int Nc, int kp) {
        wa.s[si++] = {s, d, K, Nc, kp, t0};
        t0 += (Nc / 64) * (kp / 64);
    };
    for (int t = 0; t < 5; ++t) addseg(w1f[t], w1t[t], din[t], 128, kpad[t]);
    for (int t = 0; t < 5; ++t) addseg(w2f[t], w2t[t], 128, 128, 128);
    addseg(w_xou, wxout, 640, 1920, 640);
    addseg(w_o1, wo1t, 640, 512, 640);
    wt_kernel<<<t0, 256, 0, stream>>>(wa);

    // 2) fused MLPs (f32 convert inline) -> x
    MlpArgs ma;
    for (int t = 0; t < 5; ++t) {
        ma.p[t] = {feats[t], w1t[t], b1f[t], w2t[t], b2f[t]};
        ma.din[t] = din[t]; ma.kpad[t] = kpad[t];
    }
    mlp_kernel<<<dim3(MP / 128, 5), 256, 0, stream>>>(ma, xbf);

    // 3) xou GEMM + fused gates (r7 schedule, 32x32x16 MFMA, XCD-swizzled)
    xou_kernel<<<2560, 256, 0, stream>>>(xbf, wxout, b_xou, ffb, rrb, cc);

    // 4) tree recursion (LDS) + h
    levels_h_kernel<<<dim3(NT, 20), 256, 0, stream>>>(cc, ffb, rrb, xbf, hbf);

    // 5) readout: o1 GEMM fused with w_o2 dot -> outacc, then sigmoid
    hipMemsetAsync(outacc, 0, (size_t)MP * 4, stream);
    gemm_db_kernel<<<1024, 256, 0, stream>>>(hbf, wo1t, b_o1, w_o2, outacc);
    sig_kernel<<<(NN + 255) / 256, 256, 0, stream>>>(outacc, b_o2, outp);
}

// Round 11
// 228.515 us; speedup vs baseline: 1.0832x; 1.0832x over previous
//
#include <hip/hip_runtime.h>
#include <hip/hip_bf16.h>

typedef __hip_bfloat16 bf16;
typedef __attribute__((ext_vector_type(8))) short bfrag8;  // 8 bf16 = 4 VGPRs
typedef __attribute__((ext_vector_type(4))) float f4;

#define NN 32704      // total nodes = 64 trees * 511
#define MP 32768      // M padded to 128-multiple
#define PT 511
#define NT 64
#define XD 640

union bfu8 { bfrag8 v; bf16 h[8]; };
union bfu4 { uint2 u; bf16 h[4]; };

__device__ __forceinline__ float fast_sigmoid(float x) {
    float e = exp2f(-1.44269504f * x);
    return __builtin_amdgcn_rcpf(1.0f + e);
}
__device__ __forceinline__ float fast_tanh(float x) {
    float e = exp2f(2.88539008f * x);
    return 1.0f - 2.0f * __builtin_amdgcn_rcpf(e + 1.0f);
}

// async global->LDS, 16B/lane. LDS dest linear; swizzle applied on GLOBAL source (m173).
__device__ __forceinline__ void gload16(const bf16* g, char* l) {
    __builtin_amdgcn_global_load_lds(
        (const __attribute__((address_space(1))) unsigned int*)(g),
        (__attribute__((address_space(3))) unsigned int*)(l), 16, 0, 0);
}

// ---------------- weight transpose-convert: all 12 weights, one launch ----------------
struct WtSeg { const float* src; bf16* dst; int K, Nc, kpad, tile0; };
struct WtArgs { WtSeg s[12]; };
__global__ __launch_bounds__(256) void wt_kernel(WtArgs a) {
    int bid = blockIdx.x;
    int si = 0;
#pragma unroll
    for (int i = 1; i < 12; ++i) if (bid >= a.s[i].tile0) si = i;
    WtSeg sg = a.s[si];
    int local = bid - sg.tile0;
    int kt = sg.kpad >> 6;
    int nb = local / kt, kb = local - nb * kt;
    int n0 = nb * 64, k0 = kb * 64;

    __shared__ float T[64][65];
    int tid = threadIdx.x;
    int kk = tid >> 2, nq = (tid & 3) * 16;
    bool kval = (k0 + kk) < sg.K;
    const float* srow = sg.src + (size_t)(k0 + kk) * sg.Nc + n0 + nq;
#pragma unroll
    for (int c = 0; c < 4; ++c) {
        float4 v = kval ? *(const float4*)(srow + c * 4) : float4{0, 0, 0, 0};
        T[kk][nq + c * 4 + 0] = v.x; T[kk][nq + c * 4 + 1] = v.y;
        T[kk][nq + c * 4 + 2] = v.z; T[kk][nq + c * 4 + 3] = v.w;
    }
    __syncthreads();
    int n = tid >> 2;
#pragma unroll
    for (int c = 0; c < 2; ++c) {
        int k8 = (tid & 3) * 2 + c;
        bfu8 u;
#pragma unroll
        for (int j = 0; j < 8; ++j) u.h[j] = __float2bfloat16(T[k8 * 8 + j][n]);
        *(bfrag8*)(sg.dst + (size_t)(n0 + n) * sg.kpad + k0 + k8 * 8) = u.v;
    }
}

// ---------------- fused MLP: f32-feat inline convert + 2 layers, hid1 in LDS ----------------
struct MlpP { const float* feat; const bf16* w1; const float* b1; const bf16* w2; const float* b2; };
struct MlpArgs { MlpP p[5]; int din[5]; int kpad[5]; };
__global__ __launch_bounds__(256) void mlp_kernel(MlpArgs args, bf16* __restrict__ out) {
    __shared__ __align__(16) char smem[64 * 1024];
    char* As = smem;            // [128][128B] feat k-tile (bf16, swizzled)
    char* Bs = smem + 16384;    // [128][128B] w1 k-tile
    char* Hs = smem + 32768;    // [128][256B] hid1 (bf16, swizzled)
    int t = blockIdx.y;
    int K = args.kpad[t], din = args.din[t];
    MlpP p = args.p[t];
    int tid = threadIdx.x, lane = tid & 63, w = tid >> 6;
    int brow = blockIdx.x * 128;
    int wr = (w >> 1) * 64, wc = (w & 1) * 64;
    int am = lane & 15, ah = lane >> 4;

    f4 acc[4][4] = {};
    for (int k0 = 0; k0 < K; k0 += 64) {
#pragma unroll
        for (int r = 0; r < 4; ++r) {
            int o = r * 4096 + tid * 16;
            int row = o >> 7;
            int cb = (o & 127) ^ ((row & 7) << 4);
            gload16(p.w1 + (size_t)row * K + k0 + (cb >> 1), Bs + o);
        }
        {
            int col0 = (tid & 7) * 8;
#pragma unroll
            for (int c = 0; c < 4; ++c) {
                int row = (tid >> 3) + c * 32;
                int grow = brow + row;
                bfu8 u; u.v = (bfrag8){0,0,0,0,0,0,0,0};
                int kc = k0 + col0;
                if (grow < NN && kc < din) {
                    const float* s = p.feat + (size_t)grow * din + kc;
                    float4 x = *(const float4*)s, y = *(const float4*)(s + 4);
                    u.h[0] = __float2bfloat16(x.x); u.h[1] = __float2bfloat16(x.y);
                    u.h[2] = __float2bfloat16(x.z); u.h[3] = __float2bfloat16(x.w);
                    u.h[4] = __float2bfloat16(y.x); u.h[5] = __float2bfloat16(y.y);
                    u.h[6] = __float2bfloat16(y.z); u.h[7] = __float2bfloat16(y.w);
                }
                *(bfrag8*)(As + row * 128 + ((col0 * 2) ^ ((row & 7) << 4))) = u.v;
            }
        }
        __syncthreads();
#pragma unroll
        for (int s = 0; s < 2; ++s) {
            int cb = s * 64 + ah * 16;
            bfrag8 a[4], b[4];
#pragma unroll
            for (int f = 0; f < 4; ++f) {
                int ra = wr + f * 16 + am;
                a[f] = *(const bfrag8*)(As + ra * 128 + (cb ^ ((ra & 7) << 4)));
                int rb = wc + f * 16 + am;
                b[f] = *(const bfrag8*)(Bs + rb * 128 + (cb ^ ((rb & 7) << 4)));
            }
#pragma unroll
            for (int i = 0; i < 4; ++i)
#pragma unroll
                for (int j = 0; j < 4; ++j)
                    acc[i][j] = __builtin_amdgcn_mfma_f32_16x16x32_bf16(a[i], b[j], acc[i][j], 0, 0, 0);
        }
        __syncthreads();
    }
#pragma unroll
    for (int i = 0; i < 4; ++i)
#pragma unroll
        for (int j = 0; j < 4; ++j) {
            int col = wc + j * 16 + am;
            float bb = p.b1[col];
#pragma unroll
            for (int r = 0; r < 4; ++r) {
                int row = wr + i * 16 + ah * 4 + r;
                float v = fmaxf(acc[i][j][r] + bb, 0.0f);
                *(bf16*)(Hs + row * 256 + ((col * 2) ^ ((row & 7) << 4))) = __float2bfloat16(v);
            }
        }
    __syncthreads();
    f4 acc2[4][4] = {};
#pragma unroll
    for (int ks = 0; ks < 4; ++ks) {
        bfrag8 a[4], b[4];
        int kb = ks * 64 + ah * 16;
#pragma unroll
        for (int f = 0; f < 4; ++f) {
            int ra = wr + f * 16 + am;
            a[f] = *(const bfrag8*)(Hs + ra * 256 + (kb ^ ((ra & 7) << 4)));
            int cbn = wc + f * 16 + am;
            b[f] = *(const bfrag8*)(p.w2 + (size_t)cbn * 128 + ks * 32 + ah * 8);
        }
#pragma unroll
        for (int i = 0; i < 4; ++i)
#pragma unroll
            for (int j = 0; j < 4; ++j)
                acc2[i][j] = __builtin_amdgcn_mfma_f32_16x16x32_bf16(a[i], b[j], acc2[i][j], 0, 0, 0);
    }
#pragma unroll
    for (int i = 0; i < 4; ++i)
#pragma unroll
        for (int j = 0; j < 4; ++j) {
            int col = wc + j * 16 + am;
            float bb = p.b2[col];
#pragma unroll
            for (int r = 0; r < 4; ++r) {
                int row = brow + wr + i * 16 + ah * 4 + r;
                float v = fmaxf(acc2[i][j][r] + bb, 0.0f);
                out[(size_t)row * XD + t * 128 + col] = __float2bfloat16(v);
            }
        }
}

// ---------------- xou GEMM: 2-buf BK=64 counted-vmcnt (r5 schedule) + T5 setprio ----------------
// 1D grid 2560, bijective XCD swizzle; bf16 ff epilogue.
__global__ __launch_bounds__(256) void xou_kernel(
    const bf16* __restrict__ X, const bf16* __restrict__ Wt,
    const float* __restrict__ bias,
    bf16* __restrict__ ffp, bf16* __restrict__ rrp, float* __restrict__ cc)
{
    __shared__ __align__(16) char smem[80 * 1024];   // 2 x (A 16K + B 24K)
    int bid = blockIdx.x;
    int swz = (bid & 7) * 320 + (bid >> 3);          // bijective XCD swizzle, nwg=2560
    int bcol = (swz % 10) * 64;
    int brow = (swz / 10) * 128;
    int tid = threadIdx.x, lane = tid & 63, w = tid >> 6;
    int wr = (w >> 1) * 64, wc = (w & 1) * 32;
    int am = lane & 15, ah = lane >> 4;

    auto stage = [&](int buf, int k0) {   // 10 load instructions per lane
        char* As = smem + buf * 40960;
        char* Bs = As + 16384;
#pragma unroll
        for (int r = 0; r < 4; ++r) {
            int o = r * 4096 + tid * 16;
            int row = o >> 7;
            int cb = (o & 127) ^ ((row & 7) << 4);
            gload16(X + (size_t)(brow + row) * XD + k0 + (cb >> 1), As + o);
        }
#pragma unroll
        for (int r = 0; r < 6; ++r) {
            int o = r * 4096 + tid * 16;
            int row = o >> 7;
            int q = row >> 6, rl = row & 63;
            int cb = (o & 127) ^ ((row & 7) << 4);
            gload16(Wt + (size_t)(q * 640 + bcol + rl) * XD + k0 + (cb >> 1), Bs + o);
        }
    };

    f4 acc[3][4][2] = {};
    auto compute = [&](int buf) {
        char* As = smem + buf * 40960;
        char* Bs = As + 16384;
#pragma unroll
        for (int s = 0; s < 2; ++s) {
            int cb = s * 64 + ah * 16;
            bfrag8 a[4], b[3][2];
#pragma unroll
            for (int f = 0; f < 4; ++f) {
                int ra = wr + f * 16 + am;
                a[f] = *(const bfrag8*)(As + ra * 128 + (cb ^ ((ra & 7) << 4)));
            }
#pragma unroll
            for (int q = 0; q < 3; ++q)
#pragma unroll
                for (int f = 0; f < 2; ++f) {
                    int rb = wc + f * 16 + am;
                    b[q][f] = *(const bfrag8*)(Bs + q * 8192 + rb * 128 + (cb ^ ((rb & 7) << 4)));
                }
            __builtin_amdgcn_s_setprio(1);
#pragma unroll
            for (int q = 0; q < 3; ++q)
#pragma unroll
                for (int i = 0; i < 4; ++i)
#pragma unroll
                    for (int j = 0; j < 2; ++j)
                        acc[q][i][j] = __builtin_amdgcn_mfma_f32_16x16x32_bf16(a[i], b[q][j], acc[q][i][j], 0, 0, 0);
            __builtin_amdgcn_s_setprio(0);
        }
    };

    stage(0, 0);
    stage(1, 64);
    for (int kt = 0; kt < 8; ++kt) {
        asm volatile("s_waitcnt vmcnt(10)" ::: "memory");  // tile kt landed; kt+1 in flight
        __builtin_amdgcn_s_barrier();
        compute(kt & 1);
        __builtin_amdgcn_s_barrier();                      // all waves done reading before overwrite
        stage(kt & 1, (kt + 2) * 64);
    }
    asm volatile("s_waitcnt vmcnt(10)" ::: "memory");
    __builtin_amdgcn_s_barrier();
    compute(0);
    asm volatile("s_waitcnt vmcnt(0)" ::: "memory");
    __builtin_amdgcn_s_barrier();
    compute(1);

#pragma unroll
    for (int i = 0; i < 4; ++i)
#pragma unroll
        for (int j = 0; j < 2; ++j) {
            int col = bcol + wc + j * 16 + am;
            float bxx = bias[col], bff = bias[640 + col], brr = bias[1280 + col];
#pragma unroll
            for (int r = 0; r < 4; ++r) {
                int row = brow + wr + i * 16 + ah * 4 + r;
                size_t o = (size_t)row * XD + col;
                float xx = acc[0][i][j][r] + bxx;
                float fv = fast_sigmoid(acc[1][i][j][r] + bff);
                float rv = fast_sigmoid(acc[2][i][j][r] + brr);
                unsigned pl = (unsigned)row % 511u;
                if (pl < 255u) ffp[o] = __float2bfloat16(fv);  // ff read only for internal nodes
                rrp[o] = __float2bfloat16(rv);
                if (row < NN) cc[o] = (1.0f - fv) * xx;
            }
        }
}

// ---------------- tree recursion in LDS + h, one launch ----------------
__device__ __forceinline__ int clidx(int node, int e) {
    int g = e & ~3;
    return node * 32 + (g ^ ((node & 7) * 4)) + (e & 3);
}
__global__ __launch_bounds__(256) void levels_h_kernel(
    float* __restrict__ c, const bf16* __restrict__ ff,
    const bf16* __restrict__ rr, const bf16* __restrict__ x, bf16* __restrict__ h) {
    __shared__ __align__(16) float cl[511 * 32];   // 65,408 B
    int t = blockIdx.x, d0 = blockIdx.y * 32;
    size_t tb = (size_t)t * PT;
    int tid = threadIdx.x;

    for (int it = tid; it < 511 * 8; it += 256) {
        int node = it >> 3, q = (it & 7) * 4;
        *(float4*)&cl[clidx(node, q)] = *(const float4*)(c + (tb + node) * XD + d0 + q);
    }
    __syncthreads();

    for (int n = 1; n <= 8; ++n) {
        int cnt = 1 << (8 - n);
        for (int it = tid; it < cnt * 8; it += 256) {
            int pl = (cnt - 1) + (it >> 3), q = (it & 7) * 4;
            bfu4 fu; fu.u = *(const uint2*)(ff + (tb + pl) * XD + d0 + q);
            float4 l  = *(const float4*)&cl[clidx(2 * pl + 1, q)];
            float4 rg = *(const float4*)&cl[clidx(2 * pl + 2, q)];
            float4 cv = *(const float4*)&cl[clidx(pl, q)];
            cv.x += __bfloat162float(fu.h[0]) * (l.x + rg.x);
            cv.y += __bfloat162float(fu.h[1]) * (l.y + rg.y);
            cv.z += __bfloat162float(fu.h[2]) * (l.z + rg.z);
            cv.w += __bfloat162float(fu.h[3]) * (l.w + rg.w);
            *(float4*)&cl[clidx(pl, q)] = cv;
        }
        __syncthreads();
    }

    for (int it = tid; it < 255 * 8; it += 256) {
        int pl = it >> 3, q = (it & 7) * 4;
        *(float4*)(c + (tb + pl) * XD + d0 + q) = *(const float4*)&cl[clidx(pl, q)];
    }
    for (int it = tid; it < 511 * 4; it += 256) {
        int node = it >> 2, q = (it & 3) * 8;
        size_t o = (tb + node) * XD + d0 + q;
        bfu8 rv, xv, ov;
        rv.v = *(const bfrag8*)(rr + o);
        xv.v = *(const bfrag8*)(x + o);
        float4 c0 = *(const float4*)&cl[clidx(node, q)];
        float4 c1 = *(const float4*)&cl[clidx(node, q + 4)];
        float cv[8] = {c0.x, c0.y, c0.z, c0.w, c1.x, c1.y, c1.z, c1.w};
#pragma unroll
        for (int j = 0; j < 8; ++j) {
            float r = __bfloat162float(rv.h[j]);
            float xb = __bfloat162float(xv.h[j]);
            ov.h[j] = __float2bfloat16(r * fast_tanh(cv[j]) + (1.0f - r) * xb);
        }
        *(bfrag8*)(h + o) = ov.v;
    }
}

// ---------------- o1 GEMM fused with w_o2 dot: atomicAdd partial row sums ----------------
__global__ __launch_bounds__(256) void gemm_db_kernel(
    const bf16* __restrict__ A, const bf16* __restrict__ Bt,
    const float* __restrict__ bias, const float* __restrict__ w2,
    float* __restrict__ outacc)
{
    __shared__ __align__(16) char smem[64 * 1024];
    int bid = blockIdx.x;
    int swz = (bid & 7) * 128 + (bid >> 3);          // bijective, nwg=1024
    int bcol = (swz & 3) * 128;
    int brow = (swz >> 2) * 128;
    int tid = threadIdx.x, lane = tid & 63, w = tid >> 6;
    int wr = (w >> 1) * 64, wc = (w & 1) * 64;
    int am = lane & 15, ah = lane >> 4;

    auto stage = [&](int buf, int k0) {
        char* As = smem + buf * 32768;
        char* Bs = As + 16384;
#pragma unroll
        for (int r = 0; r < 4; ++r) {
            int o = r * 4096 + tid * 16;
            int row = o >> 7;
            int cb = (o & 127) ^ ((row & 7) << 4);
            gload16(A + (size_t)(brow + row) * XD + k0 + (cb >> 1), As + o);
            gload16(Bt + (size_t)(bcol + row) * XD + k0 + (cb >> 1), Bs + o);
        }
    };

    f4 acc[4][4] = {};
    auto compute = [&](int buf) {
        char* As = smem + buf * 32768;
        char* Bs = As + 16384;
#pragma unroll
        for (int s = 0; s < 2; ++s) {
            int cb = s * 64 + ah * 16;
            bfrag8 a[4], b[4];
#pragma unroll
            for (int f = 0; f < 4; ++f) {
                int ra = wr + f * 16 + am;
                a[f] = *(const bfrag8*)(As + ra * 128 + (cb ^ ((ra & 7) << 4)));
                int rb = wc + f * 16 + am;
                b[f] = *(const bfrag8*)(Bs + rb * 128 + (cb ^ ((rb & 7) << 4)));
            }
            __builtin_amdgcn_s_setprio(1);
#pragma unroll
            for (int i = 0; i < 4; ++i)
#pragma unroll
                for (int j = 0; j < 4; ++j)
                    acc[i][j] = __builtin_amdgcn_mfma_f32_16x16x32_bf16(a[i], b[j], acc[i][j], 0, 0, 0);
            __builtin_amdgcn_s_setprio(0);
        }
    };

    stage(0, 0);
    stage(1, 64);
    for (int kt = 0; kt < 8; ++kt) {
        asm volatile("s_waitcnt vmcnt(8)" ::: "memory");
        __builtin_amdgcn_s_barrier();
        compute(kt & 1);
        __builtin_amdgcn_s_barrier();
        stage(kt & 1, (kt + 2) * 64);
    }
    asm volatile("s_waitcnt vmcnt(8)" ::: "memory");
    __builtin_amdgcn_s_barrier();
    compute(0);
    asm volatile("s_waitcnt vmcnt(0)" ::: "memory");
    __builtin_amdgcn_s_barrier();
    compute(1);

    // epilogue: hid2 = relu(acc+bias); partial dot with w_o2 cols; reduce over 16 lanes; atomic
    float w2v[4];
#pragma unroll
    for (int j = 0; j < 4; ++j) w2v[j] = w2[bcol + wc + j * 16 + am];
#pragma unroll
    for (int i = 0; i < 4; ++i) {
        float ps[4] = {0.0f, 0.0f, 0.0f, 0.0f};
#pragma unroll
        for (int j = 0; j < 4; ++j) {
            float bb = bias[bcol + wc + j * 16 + am];
#pragma unroll
            for (int r = 0; r < 4; ++r)
                ps[r] += fmaxf(acc[i][j][r] + bb, 0.0f) * w2v[j];
        }
#pragma unroll
        for (int r = 0; r < 4; ++r) {
            float s = ps[r];
            s += __shfl_xor(s, 1, 64);
            s += __shfl_xor(s, 2, 64);
            s += __shfl_xor(s, 4, 64);
            s += __shfl_xor(s, 8, 64);
            if (am == 0) {
                int row = brow + wr + i * 16 + ah * 4 + r;
                if (row < NN) atomicAdd(outacc + row, s);
            }
        }
    }
}

// ---------------- out = sigmoid(acc + b_o2) ----------------
__global__ void sig_kernel(const float* __restrict__ acc, const float* __restrict__ b2,
                           float* __restrict__ out) {
    int i = blockIdx.x * 256 + threadIdx.x;
    if (i < NN) out[i] = fast_sigmoid(acc[i] + b2[0]);
}

// ---------------- host ----------------
extern "C" void kernel_launch(void* const* d_in, const int* in_sizes, int n_in,
                              void* d_out, int out_size, void* d_ws, size_t ws_size,
                              hipStream_t stream) {
    const int din[5]  = {32, 64, 256, 128, 16};
    const int kpad[5] = {64, 64, 256, 128, 64};

    const float* feats[5];
    const float *w1f[5], *b1f[5], *w2f[5], *b2f[5];
    for (int t = 0; t < 5; ++t) {
        feats[t] = (const float*)d_in[t];
        w1f[t] = (const float*)d_in[8 + 4 * t];
        b1f[t] = (const float*)d_in[9 + 4 * t];
        w2f[t] = (const float*)d_in[10 + 4 * t];
        b2f[t] = (const float*)d_in[11 + 4 * t];
    }
    const float* w_xou = (const float*)d_in[28];
    const float* b_xou = (const float*)d_in[29];
    const float* w_o1  = (const float*)d_in[30];
    const float* b_o1  = (const float*)d_in[31];
    const float* w_o2  = (const float*)d_in[32];
    const float* b_o2  = (const float*)d_in[33];

    float* outp = (float*)d_out;
    float* cc   = (float*)d_out + NN;

    char* ws = (char*)d_ws;
    size_t off = 0;
    auto take = [&](size_t bytes) -> char* {
        char* p = ws + off;
        off += (bytes + 255) & ~(size_t)255;
        return p;
    };
    bf16* w1t[5]; for (int t = 0; t < 5; ++t) w1t[t] = (bf16*)take((size_t)128 * kpad[t] * 2);
    bf16* w2t[5]; for (int t = 0; t < 5; ++t) w2t[t] = (bf16*)take((size_t)128 * 128 * 2);
    bf16* wxout = (bf16*)take((size_t)1920 * 640 * 2);
    bf16* wo1t  = (bf16*)take((size_t)512 * 640 * 2);
    bf16* hbf   = (bf16*)take((size_t)MP * XD * 2);
    bf16* xbf   = (bf16*)take((size_t)MP * XD * 2);
    bf16* ffb   = (bf16*)take((size_t)MP * XD * 2);
    bf16* rrb   = (bf16*)take((size_t)MP * XD * 2);
    float* outacc = (float*)take((size_t)MP * 4);

    // 1) weight transpose-converts (one launch)
    WtArgs wa;
    int t0 = 0, si = 0;
    auto addseg = [&](const float* s, bf16* d, int K, int Nc, int kp) {
        wa.s[si++] = {s, d, K, Nc, kp, t0};
        t0 += (Nc / 64) * (kp / 64);
    };
    for (int t = 0; t < 5; ++t) addseg(w1f[t], w1t[t], din[t], 128, kpad[t]);
    for (int t = 0; t < 5; ++t) addseg(w2f[t], w2t[t], 128, 128, 128);
    addseg(w_xou, wxout, 640, 1920, 640);
    addseg(w_o1, wo1t, 640, 512, 640);
    wt_kernel<<<t0, 256, 0, stream>>>(wa);

    // 2) fused MLPs (f32 convert inline) -> x
    MlpArgs ma;
    for (int t = 0; t < 5; ++t) {
        ma.p[t] = {feats[t], w1t[t], b1f[t], w2t[t], b2f[t]};
        ma.din[t] = din[t]; ma.kpad[t] = kpad[t];
    }
    mlp_kernel<<<dim3(MP / 128, 5), 256, 0, stream>>>(ma, xbf);

    // 3) xou GEMM + fused gates (2-buf BK=64 counted-vmcnt, XCD-swizzled)
    xou_kernel<<<2560, 256, 0, stream>>>(xbf, wxout, b_xou, ffb, rrb, cc);

    // 4) tree recursion (LDS) + h
    levels_h_kernel<<<dim3(NT, 20), 256, 0, stream>>>(cc, ffb, rrb, xbf, hbf);

    // 5) readout: o1 GEMM fused with w_o2 dot -> outacc, then sigmoid
    hipMemsetAsync(outacc, 0, (size_t)MP * 4, stream);
    gemm_db_kernel<<<1024, 256, 0, stream>>>(hbf, wo1t, b_o1, w_o2, outacc);
    sig_kernel<<<(NN + 255) / 256, 256, 0, stream>>>(outacc, b_o2, outp);
}